// Round 6
// baseline (116.543 us; speedup 1.0000x reference)
//
#include <hip/hip_runtime.h>

typedef short bf16x8 __attribute__((ext_vector_type(8)));   // 8 bf16 in 4 VGPRs
typedef float f32x4v __attribute__((ext_vector_type(4)));

// ---- constants derived from the reference ----
// grid = linspace(-1,1,12); centers c_k = -1 + (3+k)*2/11, k=0..7
// h = 0.4 + 1e-6 ; z_k = (x - c_k)/h = u - k*DLT,  u = (x - c0)/h
// basis_k = exp(-z_k^2/2) = exp2(A2*u^2) * exp2(B2*u)^k * exp2(GCF*k^2)
// exp2(GCF*k^2) is constant per k and folded into the weights at prep time.
constexpr double H_D    = 0.4 + 1e-6;
constexpr double INVH_D = 1.0 / H_D;
constexpr double C0_D   = -1.0 + 6.0 / 11.0;
constexpr double DLT_D  = (2.0 / 11.0) / H_D;
constexpr double L2E_D  = 1.4426950408889634;

constexpr float INVH = (float)INVH_D;
constexpr float NC0H = (float)(-C0_D * INVH_D);           // u = x*INVH + NC0H
constexpr float A2f  = (float)(-0.5 * L2E_D);             // E0 = exp2(A2*u*u)
constexpr float B2f  = (float)(DLT_D * L2E_D);            // r  = exp2(B2*u)
constexpr float GCF  = (float)(-0.5 * DLT_D * DLT_D * L2E_D); // g_k = exp2(GCF*k*k)
constexpr float NL2E = (float)(-L2E_D);

__device__ __forceinline__ float fexp2(float v) {
#if __has_builtin(__builtin_amdgcn_exp2f)
  return __builtin_amdgcn_exp2f(v);
#else
  return exp2f(v);
#endif
}
__device__ __forceinline__ float frcp(float v) {
#if __has_builtin(__builtin_amdgcn_rcpf)
  return __builtin_amdgcn_rcpf(v);
#else
  return 1.0f / v;
#endif
}
__device__ __forceinline__ float siluf(float v) {
  // v * sigmoid(v) = v / (1 + 2^(-log2e * v))
  return v * frcp(1.0f + fexp2(NL2E * v));
}
// pack two fp32 -> one dword of two bf16 (round-half-up), via v_perm_b32
__device__ __forceinline__ unsigned pk2(float lo, float hi) {
  unsigned a = __float_as_uint(hi) + 0x8000u;
  unsigned b = __float_as_uint(lo) + 0x8000u;
  return __builtin_amdgcn_perm(a, b, 0x07060302u); // [a.hi16 : b.hi16]
}
__device__ __forceinline__ bf16x8 packfrag(const float (&v)[8]) {
  uint4 d;
  d.x = pk2(v[0], v[1]);
  d.y = pk2(v[2], v[3]);
  d.z = pk2(v[4], v[5]);
  d.w = pk2(v[6], v[7]);
  return __builtin_bit_cast(bf16x8, d);
}
// RNE fp32 -> bf16 (prep path)
__device__ __forceinline__ unsigned rne16(float f) {
  unsigned u = __float_as_uint(f);
  return (u + 0x7fffu + ((u >> 16) & 1u)) >> 16;
}

// ---------------- prep: build fragment-ordered bf16 weights + bias ----------------
// K ordering: k = G*288 + t*32 + c   (G=0..3 channel-groups of 32, t=0..8 feature,
//                                     c = quad*8 + j channel within group)
// Fragment entry e = (G*9+t)*2 + h  (h = column half), lane l: col n = h*16 + (l&15),
// channels cbase = G*32 + (l>>4)*8 + (0..7)  -> matches MFMA B[k=quad*8+j][n=lane&15].
__global__ void kan_prep(const float* __restrict__ coeff,
                         const float* __restrict__ bw,
                         const float* __restrict__ bb,
                         const float* __restrict__ ew,
                         uint4* __restrict__ wfrag,
                         float* __restrict__ bias) {
  if (blockIdx.x == 18) {
    // bias[n] = sum_i ew[i][n]*bb[i][n]; 256 thr = 32 n × 8 chunks of 16 i
    __shared__ float part[256];
    const int n = threadIdx.x & 31;
    const int c = threadIdx.x >> 5;
    float s = 0.f;
#pragma unroll
    for (int i = c * 16; i < c * 16 + 16; ++i)
      s += ew[i * 32 + n] * bb[i * 32 + n];
    part[threadIdx.x] = s;
    __syncthreads();
    if (threadIdx.x < 32) {
      float t = 0.f;
#pragma unroll
      for (int c2 = 0; c2 < 8; ++c2) t += part[c2 * 32 + threadIdx.x];
      bias[threadIdx.x] = t;
    }
    return;
  }
  const int e    = blockIdx.x * 4 + (threadIdx.x >> 6); // 0..71  (= s*2 + h)
  const int lane = threadIdx.x & 63;
  const int s = e >> 1, h = e & 1;
  const int G = s / 9, t = s % 9;
  const int n = h * 16 + (lane & 15);
  const int cbase = G * 32 + (lane >> 4) * 8;
  float v[8];
  if (t == 0) {
#pragma unroll
    for (int j = 0; j < 8; ++j) {
      int i = cbase + j;
      v[j] = ew[i * 32 + n] * bw[i * 32 + n];
    }
  } else {
    const int k = t - 1;
    const float g = exp2f(GCF * (float)(k * k)); // fold g_k into weight
#pragma unroll
    for (int j = 0; j < 8; ++j) {
      int i = cbase + j;
      v[j] = ew[i * 32 + n] * coeff[(i * 32 + n) * 8 + k] * g;
    }
  }
  uint4 d;
  d.x = (rne16(v[1]) << 16) | rne16(v[0]);
  d.y = (rne16(v[3]) << 16) | rne16(v[2]);
  d.z = (rne16(v[5]) << 16) | rne16(v[4]);
  d.w = (rne16(v[7]) << 16) | rne16(v[6]);
  wfrag[e * 64 + lane] = d;
}

// async global->LDS, 16B per lane; LDS dest must be wave-uniform base + lane*16
// (it is: dest index = tid + i*256 -> per wave: uniform base + lane).
__device__ __forceinline__ void gl_lds16(const uint4* g, uint4* l) {
  __builtin_amdgcn_global_load_lds(
      (const __attribute__((address_space(1))) void*)g,
      (__attribute__((address_space(3))) void*)l, 16, 0, 0);
}

__device__ __forceinline__ void stage_g(const uint4* __restrict__ src,
                                        uint4* __restrict__ dst, int tid) {
#pragma unroll
  for (int i = 0; i < 4; ++i) gl_lds16(src + tid + i * 256, dst + tid + i * 256);
  if (tid < 128) gl_lds16(src + 1024 + tid, dst + 1024 + tid);
}

__device__ __forceinline__ void load_x8(float (&xb)[2][8],
                                        const float* __restrict__ xbase,
                                        int coloff) {
#pragma unroll
  for (int tl = 0; tl < 2; ++tl) {
    const float4* p =
        reinterpret_cast<const float4*>(xbase + (long)tl * 16 * 128 + coloff);
    float4 a = p[0], b = p[1];
    xb[tl][0] = a.x; xb[tl][1] = a.y; xb[tl][2] = a.z; xb[tl][3] = a.w;
    xb[tl][4] = b.x; xb[tl][5] = b.y; xb[tl][6] = b.z; xb[tl][7] = b.w;
  }
}

// ---------------- main: fused feature-gen + MFMA GEMM ----------------
// 2 row-tiles (32 rows) per wave — each LDS weight fragment read once feeds 2
// MFMAs (halves LDS-pipe cost vs 1-tile). Weight staging is double-buffered:
// the DMA for G+1 issues BEFORE G's t-loop, so the barrier after the t-loop
// finds it drained (no per-G staging-latency bubble). 36.9 KB LDS, 4 blk/CU.
__global__ __launch_bounds__(256, 4) void kan_main(
    const float* __restrict__ x,
    const uint4* __restrict__ wfrag,
    const float* __restrict__ bias,
    float* __restrict__ out) {
  __shared__ uint4 wlds[2][1152];
  const int tid  = threadIdx.x;
  const int lane = tid & 63;
  const int wave = tid >> 6;
  const int m    = lane & 15;  // A row-in-tile; also C/D column (within half)
  const int quad = lane >> 4;  // A channel-octet selector; C/D row group
  const long rowbase = ((long)blockIdx.x * 4 + wave) * 32;

  f32x4v acc[2][2];
#pragma unroll
  for (int tl = 0; tl < 2; ++tl)
#pragma unroll
    for (int hh = 0; hh < 2; ++hh)
#pragma unroll
      for (int rr = 0; rr < 4; ++rr) acc[tl][hh][rr] = 0.f;

  // per-lane x base: row (rowbase + tl*16 + m), octet quad*8, group G*32
  const float* xbase = x + (rowbase + m) * 128 + (long)quad * 8;

  float xb[2][8];
  load_x8(xb, xbase, 0);        // G=0 x in flight with staging
  stage_g(wfrag, wlds[0], tid); // G=0 weights via DMA
  const float bv0 = bias[m];
  const float bv1 = bias[m + 16];
  __syncthreads();              // one-time startup drain (x0 + stage0)

#pragma unroll 1
  for (int G = 0; G < 4; ++G) {
    // ---- issue next G's staging DMA now; drains at the barrier below ----
    if (G < 3) stage_g(wfrag + (size_t)(G + 1) * 1152, wlds[(G + 1) & 1], tid);

    // ---- consume xb into compact per-G state ----
    bf16x8 af0[2];
    float pg[2][8], rg[2][8];
#pragma unroll
    for (int tl = 0; tl < 2; ++tl) {
      float sv[8];
#pragma unroll
      for (int j = 0; j < 8; ++j) sv[j] = siluf(xb[tl][j]);
      af0[tl] = packfrag(sv);
#pragma unroll
      for (int j = 0; j < 8; ++j) {
        float u = fmaf(xb[tl][j], INVH, NC0H);
        pg[tl][j] = fexp2(A2f * u * u);
        rg[tl][j] = fexp2(B2f * u);
      }
    }

    // ---- prefetch next G's x (consumed after the barrier) ----
    if (G < 3) load_x8(xb, xbase, (G + 1) * 32);

    const uint4* wl = wlds[G & 1] + lane;

    // ---- t = 0 : silu feature ----
#pragma unroll
    for (int tl = 0; tl < 2; ++tl) {
      acc[tl][0] = __builtin_amdgcn_mfma_f32_16x16x32_bf16(
          af0[tl], __builtin_bit_cast(bf16x8, wl[0]), acc[tl][0], 0, 0, 0);
      acc[tl][1] = __builtin_amdgcn_mfma_f32_16x16x32_bf16(
          af0[tl], __builtin_bit_cast(bf16x8, wl[64]), acc[tl][1], 0, 0, 0);
    }

    // ---- t = 1..8 : gaussian recurrence (g_k folded into weights) ----
#pragma unroll
    for (int t = 1; t <= 8; ++t) {
      bf16x8 c0 = __builtin_bit_cast(bf16x8, wl[t * 128]);
      bf16x8 c1 = __builtin_bit_cast(bf16x8, wl[t * 128 + 64]);
#pragma unroll
      for (int tl = 0; tl < 2; ++tl) {
        bf16x8 af = packfrag(pg[tl]);
        acc[tl][0] = __builtin_amdgcn_mfma_f32_16x16x32_bf16(af, c0, acc[tl][0], 0, 0, 0);
        acc[tl][1] = __builtin_amdgcn_mfma_f32_16x16x32_bf16(af, c1, acc[tl][1], 0, 0, 0);
        if (t < 8) {
#pragma unroll
          for (int j = 0; j < 8; ++j) pg[tl][j] *= rg[tl][j];
        }
      }
    }

    // ---- switch buffers: ensures (a) next DMA drained (issued ~t-loop ago),
    //      (b) everyone is done reading wlds[G&1] before it's re-staged ----
    if (G < 3) __syncthreads();
  }

  // epilogue: C/D layout col = lane&15 (per half), row = quad*4 + reg
#pragma unroll
  for (int tl = 0; tl < 2; ++tl) {
#pragma unroll
    for (int rr = 0; rr < 4; ++rr) {
      long row = rowbase + tl * 16 + quad * 4 + rr;
      out[row * 32 + m]      = acc[tl][0][rr] + bv0;
      out[row * 32 + m + 16] = acc[tl][1][rr] + bv1;
    }
  }
}

extern "C" void kernel_launch(void* const* d_in, const int* in_sizes, int n_in,
                              void* d_out, int out_size, void* d_ws, size_t ws_size,
                              hipStream_t stream) {
  const float* x     = (const float*)d_in[0]; // (131072,128)
  const float* coeff = (const float*)d_in[1]; // (128,32,8)
  const float* bw    = (const float*)d_in[2]; // (128,32)
  const float* bb    = (const float*)d_in[3]; // (128,32)
  const float* ew    = (const float*)d_in[4]; // (128,32)

  uint4* wfrag = (uint4*)d_ws;                       // 72*64*16 = 73728 B
  float* bias  = (float*)((char*)d_ws + 73728);      // 32 floats

  kan_prep<<<19, 256, 0, stream>>>(coeff, bw, bb, ew, wfrag, bias);
  kan_main<<<1024, 256, 0, stream>>>(x, wfrag, bias, (float*)d_out);
}

// Round 7
// 116.358 us; speedup vs baseline: 1.0016x; 1.0016x over previous
//
#include <hip/hip_runtime.h>

typedef short bf16x8 __attribute__((ext_vector_type(8)));   // 8 bf16 in 4 VGPRs
typedef float f32x4v __attribute__((ext_vector_type(4)));

// ---- constants derived from the reference ----
// grid = linspace(-1,1,12); centers c_k = -1 + (3+k)*2/11, k=0..7
// h = 0.4 + 1e-6 ; z_k = (x - c_k)/h = u - k*DLT,  u = (x - c0)/h
// basis_k = exp(-z_k^2/2) = exp2(A2*u^2) * exp2(B2*u)^k * exp2(GCF*k^2)
// exp2(GCF*k^2) is constant per k and folded into the weights at prep time.
constexpr double H_D    = 0.4 + 1e-6;
constexpr double INVH_D = 1.0 / H_D;
constexpr double C0_D   = -1.0 + 6.0 / 11.0;
constexpr double DLT_D  = (2.0 / 11.0) / H_D;
constexpr double L2E_D  = 1.4426950408889634;

constexpr float INVH = (float)INVH_D;
constexpr float NC0H = (float)(-C0_D * INVH_D);           // u = x*INVH + NC0H
constexpr float A2f  = (float)(-0.5 * L2E_D);             // E0 = exp2(A2*u*u)
constexpr float B2f  = (float)(DLT_D * L2E_D);            // r  = exp2(B2*u)
constexpr float GCF  = (float)(-0.5 * DLT_D * DLT_D * L2E_D); // g_k = exp2(GCF*k*k)
constexpr float NL2E = (float)(-L2E_D);

__device__ __forceinline__ float fexp2(float v) {
#if __has_builtin(__builtin_amdgcn_exp2f)
  return __builtin_amdgcn_exp2f(v);
#else
  return exp2f(v);
#endif
}
__device__ __forceinline__ float frcp(float v) {
#if __has_builtin(__builtin_amdgcn_rcpf)
  return __builtin_amdgcn_rcpf(v);
#else
  return 1.0f / v;
#endif
}
__device__ __forceinline__ float siluf(float v) {
  // v * sigmoid(v) = v / (1 + 2^(-log2e * v))
  return v * frcp(1.0f + fexp2(NL2E * v));
}
// pack two fp32 -> one dword of two bf16 (round-half-up), via v_perm_b32
__device__ __forceinline__ unsigned pk2(float lo, float hi) {
  unsigned a = __float_as_uint(hi) + 0x8000u;
  unsigned b = __float_as_uint(lo) + 0x8000u;
  return __builtin_amdgcn_perm(a, b, 0x07060302u); // [a.hi16 : b.hi16]
}
__device__ __forceinline__ bf16x8 packfrag(const float (&v)[8]) {
  uint4 d;
  d.x = pk2(v[0], v[1]);
  d.y = pk2(v[2], v[3]);
  d.z = pk2(v[4], v[5]);
  d.w = pk2(v[6], v[7]);
  return __builtin_bit_cast(bf16x8, d);
}
// RNE fp32 -> bf16 (prep path)
__device__ __forceinline__ unsigned rne16(float f) {
  unsigned u = __float_as_uint(f);
  return (u + 0x7fffu + ((u >> 16) & 1u)) >> 16;
}

// ---------------- prep: build fragment-ordered bf16 weights + bias ----------------
// K ordering: k = G*288 + t*32 + c   (G=0..3 channel-groups of 32, t=0..8 feature,
//                                     c = quad*8 + j channel within group)
// Fragment entry e = (G*9+t)*2 + h  (h = column half), lane l: col n = h*16 + (l&15),
// channels cbase = G*32 + (l>>4)*8 + (0..7)  -> matches MFMA B[k=quad*8+j][n=lane&15].
__global__ void kan_prep(const float* __restrict__ coeff,
                         const float* __restrict__ bw,
                         const float* __restrict__ bb,
                         const float* __restrict__ ew,
                         uint4* __restrict__ wfrag,
                         float* __restrict__ bias) {
  if (blockIdx.x == 18) {
    // bias[n] = sum_i ew[i][n]*bb[i][n]; 256 thr = 32 n × 8 chunks of 16 i
    __shared__ float part[256];
    const int n = threadIdx.x & 31;
    const int c = threadIdx.x >> 5;
    float s = 0.f;
#pragma unroll
    for (int i = c * 16; i < c * 16 + 16; ++i)
      s += ew[i * 32 + n] * bb[i * 32 + n];
    part[threadIdx.x] = s;
    __syncthreads();
    if (threadIdx.x < 32) {
      float t = 0.f;
#pragma unroll
      for (int c2 = 0; c2 < 8; ++c2) t += part[c2 * 32 + threadIdx.x];
      bias[threadIdx.x] = t;
    }
    return;
  }
  const int e    = blockIdx.x * 4 + (threadIdx.x >> 6); // 0..71  (= s*2 + h)
  const int lane = threadIdx.x & 63;
  const int s = e >> 1, h = e & 1;
  const int G = s / 9, t = s % 9;
  const int n = h * 16 + (lane & 15);
  const int cbase = G * 32 + (lane >> 4) * 8;
  float v[8];
  if (t == 0) {
#pragma unroll
    for (int j = 0; j < 8; ++j) {
      int i = cbase + j;
      v[j] = ew[i * 32 + n] * bw[i * 32 + n];
    }
  } else {
    const int k = t - 1;
    const float g = exp2f(GCF * (float)(k * k)); // fold g_k into weight
#pragma unroll
    for (int j = 0; j < 8; ++j) {
      int i = cbase + j;
      v[j] = ew[i * 32 + n] * coeff[(i * 32 + n) * 8 + k] * g;
    }
  }
  uint4 d;
  d.x = (rne16(v[1]) << 16) | rne16(v[0]);
  d.y = (rne16(v[3]) << 16) | rne16(v[2]);
  d.z = (rne16(v[5]) << 16) | rne16(v[4]);
  d.w = (rne16(v[7]) << 16) | rne16(v[6]);
  wfrag[e * 64 + lane] = d;
}

// async global->LDS, 16B per lane; LDS dest must be wave-uniform base + lane*16
// (it is: dest index = tid + i*1024 -> per wave: uniform base + lane).
__device__ __forceinline__ void gl_lds16(const uint4* g, uint4* l) {
  __builtin_amdgcn_global_load_lds(
      (const __attribute__((address_space(1))) void*)g,
      (__attribute__((address_space(3))) void*)l, 16, 0, 0);
}

__device__ __forceinline__ void load_x8(float (&xb)[2][8],
                                        const float* __restrict__ xbase,
                                        int coloff) {
#pragma unroll
  for (int tl = 0; tl < 2; ++tl) {
    const float4* p =
        reinterpret_cast<const float4*>(xbase + (long)tl * 16 * 128 + coloff);
    float4 a = p[0], b = p[1];
    xb[tl][0] = a.x; xb[tl][1] = a.y; xb[tl][2] = a.z; xb[tl][3] = a.w;
    xb[tl][4] = b.x; xb[tl][5] = b.y; xb[tl][6] = b.z; xb[tl][7] = b.w;
  }
}

// ---------------- main: fused feature-gen + MFMA GEMM ----------------
// ALL weights (73.7 KB) staged into LDS once at block start; ZERO barriers in
// the steady state — every prior variant's per-G __syncthreads carried an
// implicit vmcnt(0) drain of the x prefetch (L3 latency) and convoyed all
// waves; that was the dominant stall. 1024-thr blocks (16 waves), grid=256
// (1 block/CU), 2 row-tiles/wave, 128-VGPR cap via __launch_bounds__(1024,4).
__global__ __launch_bounds__(1024, 4) void kan_main(
    const float* __restrict__ x,
    const uint4* __restrict__ wfrag,
    const float* __restrict__ bias,
    float* __restrict__ out) {
  __shared__ uint4 wlds[4608];  // 72 fragment entries * 64 lanes = 73728 B
  const int tid  = threadIdx.x;
  const int lane = tid & 63;
  const int wave = tid >> 6;    // 0..15
  const int m    = lane & 15;   // A row-in-tile; also C/D column (within half)
  const int quad = lane >> 4;   // A channel-octet selector; C/D row group
  const long rowbase = ((long)blockIdx.x * 16 + wave) * 32;

  // ---- one-time staging of the full weight set ----
#pragma unroll
  for (int i = 0; i < 4; ++i)
    gl_lds16(wfrag + tid + i * 1024, &wlds[tid + i * 1024]);
  if (tid < 512) gl_lds16(wfrag + 4096 + tid, &wlds[4096 + tid]);

  f32x4v acc[2][2];
#pragma unroll
  for (int tl = 0; tl < 2; ++tl)
#pragma unroll
    for (int hh = 0; hh < 2; ++hh)
#pragma unroll
      for (int rr = 0; rr < 4; ++rr) acc[tl][hh][rr] = 0.f;

  // per-lane x base: row (rowbase + tl*16 + m), octet quad*8, group G*32
  const float* xbase = x + (rowbase + m) * 128 + (long)quad * 8;

  float xb[2][8];
  load_x8(xb, xbase, 0);        // G=0 x in flight while staging completes
  const float bv0 = bias[m];
  const float bv1 = bias[m + 16];
  __syncthreads();              // ONLY barrier: staging (and x0) drained

#pragma unroll 1
  for (int G = 0; G < 4; ++G) {
    // ---- consume xb into compact per-G state ----
    bf16x8 af0[2];
    float pg[2][8], rg[2][8];
#pragma unroll
    for (int tl = 0; tl < 2; ++tl) {
      float sv[8];
#pragma unroll
      for (int j = 0; j < 8; ++j) sv[j] = siluf(xb[tl][j]);
      af0[tl] = packfrag(sv);
#pragma unroll
      for (int j = 0; j < 8; ++j) {
        float u = fmaf(xb[tl][j], INVH, NC0H);
        pg[tl][j] = fexp2(A2f * u * u);
        rg[tl][j] = fexp2(B2f * u);
      }
    }

    // ---- prefetch next G's x (own-wave vmcnt; consumed next G-iteration) ----
    if (G < 3) load_x8(xb, xbase, (G + 1) * 32);

    const uint4* wl = wlds + G * 1152 + lane;

    // ---- t = 0 : silu feature ----
#pragma unroll
    for (int tl = 0; tl < 2; ++tl) {
      acc[tl][0] = __builtin_amdgcn_mfma_f32_16x16x32_bf16(
          af0[tl], __builtin_bit_cast(bf16x8, wl[0]), acc[tl][0], 0, 0, 0);
      acc[tl][1] = __builtin_amdgcn_mfma_f32_16x16x32_bf16(
          af0[tl], __builtin_bit_cast(bf16x8, wl[64]), acc[tl][1], 0, 0, 0);
    }

    // ---- t = 1..8 : gaussian recurrence (g_k folded into weights) ----
#pragma unroll
    for (int t = 1; t <= 8; ++t) {
      bf16x8 c0 = __builtin_bit_cast(bf16x8, wl[t * 128]);
      bf16x8 c1 = __builtin_bit_cast(bf16x8, wl[t * 128 + 64]);
#pragma unroll
      for (int tl = 0; tl < 2; ++tl) {
        bf16x8 af = packfrag(pg[tl]);
        acc[tl][0] = __builtin_amdgcn_mfma_f32_16x16x32_bf16(af, c0, acc[tl][0], 0, 0, 0);
        acc[tl][1] = __builtin_amdgcn_mfma_f32_16x16x32_bf16(af, c1, acc[tl][1], 0, 0, 0);
        if (t < 8) {
#pragma unroll
          for (int j = 0; j < 8; ++j) pg[tl][j] *= rg[tl][j];
        }
      }
    }
  }

  // epilogue: C/D layout col = lane&15 (per half), row = quad*4 + reg
#pragma unroll
  for (int tl = 0; tl < 2; ++tl) {
#pragma unroll
    for (int rr = 0; rr < 4; ++rr) {
      long row = rowbase + tl * 16 + quad * 4 + rr;
      out[row * 32 + m]      = acc[tl][0][rr] + bv0;
      out[row * 32 + m + 16] = acc[tl][1][rr] + bv1;
    }
  }
}

extern "C" void kernel_launch(void* const* d_in, const int* in_sizes, int n_in,
                              void* d_out, int out_size, void* d_ws, size_t ws_size,
                              hipStream_t stream) {
  const float* x     = (const float*)d_in[0]; // (131072,128)
  const float* coeff = (const float*)d_in[1]; // (128,32,8)
  const float* bw    = (const float*)d_in[2]; // (128,32)
  const float* bb    = (const float*)d_in[3]; // (128,32)
  const float* ew    = (const float*)d_in[4]; // (128,32)

  uint4* wfrag = (uint4*)d_ws;                       // 72*64*16 = 73728 B
  float* bias  = (float*)((char*)d_ws + 73728);      // 32 floats

  kan_prep<<<19, 256, 0, stream>>>(coeff, bw, bb, ew, wfrag, bias);
  kan_main<<<256, 1024, 0, stream>>>(x, wfrag, bias, (float*)d_out);
}